// Round 6
// baseline (61.411 us; speedup 1.0000x reference)
//
#include <hip/hip_runtime.h>
#include <hip/hip_bf16.h>

#define H 1024
#define MAXLEN 512
#define NB 128     // blocks: 8 groups x 16
#define NT 512     // 8 waves/block

__device__ __forceinline__ float wave_reduce_sum(float a) {
    #pragma unroll
    for (int off = 32; off; off >>= 1) a += __shfl_xor(a, off);
    return a;
}
__device__ __forceinline__ float wave_reduce_max(float a) {
    #pragma unroll
    for (int off = 32; off; off >>= 1) a = fmaxf(a, __shfl_xor(a, off));
    return a;
}

// Agent-scope coherent access (bypasses non-coherent per-XCD L2s) — proven R4/R5.
// NOTE: plain loads of mutable ws data are UNSAFE across graph replays (stale
// clean L2 lines from the previous replay); always cohLoad.
__device__ __forceinline__ float cohLoad(const float* p) {
    return __hip_atomic_load(p, __ATOMIC_RELAXED, __HIP_MEMORY_SCOPE_AGENT);
}
__device__ __forceinline__ void cohStore(float* p, float v) {
    __hip_atomic_store(p, v, __ATOMIC_RELAXED, __HIP_MEMORY_SCOPE_AGENT);
}

// ws byte layout:
//   [0..1024)     8 group arrival counters (one per 128B line)
//   [1024..1152)  root counter
//   [1152..2176)  8 per-group release flags (one per 128B line)
//   [4096..)      float data: logits[512] | y1[1024] | avec[1024] | x[1024]
__device__ __forceinline__ void arrive(char* wsb, int b, unsigned phase) {
    if (threadIdx.x == 0) {
        unsigned g = (unsigned)b >> 4;                       // 16 blocks/group
        unsigned* grp  = (unsigned*)(wsb + g * 128);
        unsigned* root = (unsigned*)(wsb + 1024);
        unsigned old = __hip_atomic_fetch_add(grp, 1u, __ATOMIC_ACQ_REL,
                                              __HIP_MEMORY_SCOPE_AGENT);
        if (old == phase * 16u - 1u) {                       // last in group
            unsigned r = __hip_atomic_fetch_add(root, 1u, __ATOMIC_ACQ_REL,
                                                __HIP_MEMORY_SCOPE_AGENT);
            if (r == phase * 8u - 1u) {                      // global releaser
                #pragma unroll
                for (int i = 0; i < 8; ++i)
                    __hip_atomic_store((unsigned*)(wsb + 1152 + i * 128), phase,
                                       __ATOMIC_RELEASE, __HIP_MEMORY_SCOPE_AGENT);
            }
        }
    }
}
__device__ __forceinline__ void waitphase(char* wsb, int b, unsigned phase) {
    if (threadIdx.x == 0) {
        unsigned g = (unsigned)b >> 4;
        const unsigned* rl = (const unsigned*)(wsb + 1152 + g * 128);
        while (__hip_atomic_load(rl, __ATOMIC_RELAXED, __HIP_MEMORY_SCOPE_AGENT) < phase)
            __builtin_amdgcn_s_sleep(4);
        __builtin_amdgcn_fence(__ATOMIC_ACQUIRE, "agent");
    }
    __syncthreads();
}

__global__ void fused_decoder(const int* __restrict__ inputId,
                              const float* __restrict__ hidden,
                              const float* __restrict__ enc,
                              const float* __restrict__ embed_table,
                              const float* __restrict__ attn_w,
                              const float* __restrict__ attn_b,
                              const float* __restrict__ comb_w,
                              const float* __restrict__ comb_b,
                              const float* __restrict__ w_ih,
                              const float* __restrict__ b_ih,
                              const float* __restrict__ b_hh,
                              float* __restrict__ d_out,
                              char* __restrict__ wsb) {
    float* F      = (float*)(wsb + 4096);
    float* logits = F;             // 512
    float* y1     = F + 512;       // 1024
    float* avec   = F + 1536;      // 1024
    float* xv     = F + 2560;      // 1024

    __shared__ float vec_lds[H];
    __shared__ float w_sm[MAXLEN];
    __shared__ float part[64][8];
    __shared__ float redm[8], reds[8];

    const int tid  = threadIdx.x;   // 0..511
    const int lane = tid & 63;
    const int w    = tid >> 6;      // wave 0..7
    const int b    = blockIdx.x;    // 0..127

    const float* embed = embed_table + (size_t)inputId[0] * H;

    // ============ Phase A: logits (waves 0-3) + y1 (waves 4-7, 2 rows each) ============
    if (w < 4) {
        int row = b * 4 + w;                         // 0..511
        const float* wrow = attn_w + (size_t)row * (2 * H);
        float acc = 0.f;
        #pragma unroll
        for (int it = 0; it < 8; ++it) {
            int base = it * 256 + lane * 4;
            float4 wv = *reinterpret_cast<const float4*>(wrow + base);
            float4 cv = (it < 4)
                ? *reinterpret_cast<const float4*>(embed + base)
                : *reinterpret_cast<const float4*>(hidden + (base - H));
            acc += wv.x * cv.x + wv.y * cv.y + wv.z * cv.z + wv.w * cv.w;
        }
        acc = wave_reduce_sum(acc);
        if (lane == 0) cohStore(logits + row, acc + attn_b[row]);
    } else {
        #pragma unroll
        for (int rr = 0; rr < 2; ++rr) {
            int row = b * 8 + (w - 4) * 2 + rr;      // 0..1023
            const float* wrow = comb_w + (size_t)row * (2 * H);   // W1 half
            float acc = 0.f;
            #pragma unroll
            for (int it = 0; it < 4; ++it) {
                int base = it * 256 + lane * 4;
                float4 wv = *reinterpret_cast<const float4*>(wrow + base);
                float4 ev = *reinterpret_cast<const float4*>(embed + base);
                acc += wv.x * ev.x + wv.y * ev.y + wv.z * ev.z + wv.w * ev.w;
            }
            acc = wave_reduce_sum(acc);
            if (lane == 0) cohStore(y1 + row, acc + comb_b[row]);
        }
    }
    __syncthreads();
    arrive(wsb, b, 1);

    // ---- preload enc panel (independent of logits): 8 cols/block, 8 k's/thread ----
    const int c8  = tid & 7;                         // col within block's stripe
    const int ks  = tid >> 3;                        // 0..63
    float ev[8];
    {
        const float* ep = enc + (size_t)(ks * 8) * H + b * 8 + c8;
        #pragma unroll
        for (int i = 0; i < 8; ++i) ev[i] = ep[(size_t)i * H];
    }
    waitphase(wsb, b, 1);

    // ============ Phase B: softmax (redundant per block) + apply ============
    {
        float l = cohLoad(logits + tid);             // NT == 512 == MAXLEN
        float m = wave_reduce_max(l);
        if (lane == 0) redm[w] = m;
        __syncthreads();
        m = redm[0];
        #pragma unroll
        for (int i = 1; i < 8; ++i) m = fmaxf(m, redm[i]);
        float e = expf(l - m);
        float s = wave_reduce_sum(e);
        if (lane == 0) reds[w] = s;
        __syncthreads();
        s = 0.f;
        #pragma unroll
        for (int i = 0; i < 8; ++i) s += reds[i];
        float wgt = e / s;
        w_sm[tid] = wgt;
        if (b == 0) d_out[2048 + tid] = wgt;         // attnWeights
        __syncthreads();

        float acc = 0.f;
        #pragma unroll
        for (int i = 0; i < 8; ++i) acc += ev[i] * w_sm[ks * 8 + i];
        part[ks][c8] = acc;
        __syncthreads();
        if (tid < 8) {
            float t = 0.f;
            #pragma unroll
            for (int i = 0; i < 64; ++i) t += part[i][tid];
            cohStore(avec + b * 8 + tid, t);
        }
    }
    __syncthreads();
    arrive(wsb, b, 2);

    // ---- preload W2 row (independent of avec): 1 row/wave ----
    const int rowC = b * 8 + w;                      // 0..1023
    float4 wv2[4];
    {
        const float* wrow = comb_w + (size_t)rowC * (2 * H) + H;
        #pragma unroll
        for (int it = 0; it < 4; ++it)
            wv2[it] = *reinterpret_cast<const float4*>(wrow + it * 256 + lane * 4);
    }
    waitphase(wsb, b, 2);

    // ============ Phase C: x = relu(y1 + W2 . avec) ============
    {
        vec_lds[tid]       = cohLoad(avec + tid);
        vec_lds[tid + 512] = cohLoad(avec + tid + 512);
        __syncthreads();
        float acc = 0.f;
        #pragma unroll
        for (int it = 0; it < 4; ++it) {
            int base = it * 256 + lane * 4;
            float4 av = *reinterpret_cast<const float4*>(vec_lds + base);
            acc += wv2[it].x * av.x + wv2[it].y * av.y
                 + wv2[it].z * av.z + wv2[it].w * av.w;
        }
        acc = wave_reduce_sum(acc);
        if (lane == 0)
            cohStore(xv + rowC, fmaxf(cohLoad(y1 + rowC) + acc, 0.f));
    }
    __syncthreads();
    arrive(wsb, b, 3);

    // ---- preload w_ih rows (independent of x): 1 j/wave, 3 gates ----
    const int j = b * 8 + w;                         // 0..1023
    float4 ar[4], az[4], an[4];
    {
        const float* wr = w_ih + (size_t)j * H;
        const float* wz = w_ih + (size_t)(H + j) * H;
        const float* wn = w_ih + (size_t)(2 * H + j) * H;
        #pragma unroll
        for (int it = 0; it < 4; ++it) {
            int base = it * 256 + lane * 4;
            ar[it] = *reinterpret_cast<const float4*>(wr + base);
            az[it] = *reinterpret_cast<const float4*>(wz + base);
            an[it] = *reinterpret_cast<const float4*>(wn + base);
        }
    }
    waitphase(wsb, b, 3);

    // ============ Phase D: GRU (h0 = 0 -> gh = b_hh) ============
    {
        vec_lds[tid]       = cohLoad(xv + tid);
        vec_lds[tid + 512] = cohLoad(xv + tid + 512);
        __syncthreads();
        float acc0 = 0.f, acc1 = 0.f, acc2 = 0.f;
        #pragma unroll
        for (int it = 0; it < 4; ++it) {
            int base = it * 256 + lane * 4;
            float4 xf = *reinterpret_cast<const float4*>(vec_lds + base);
            acc0 += ar[it].x * xf.x + ar[it].y * xf.y + ar[it].z * xf.z + ar[it].w * xf.w;
            acc1 += az[it].x * xf.x + az[it].y * xf.y + az[it].z * xf.z + az[it].w * xf.w;
            acc2 += an[it].x * xf.x + an[it].y * xf.y + an[it].z * xf.z + an[it].w * xf.w;
        }
        #pragma unroll
        for (int off = 32; off; off >>= 1) {
            acc0 += __shfl_xor(acc0, off);
            acc1 += __shfl_xor(acc1, off);
            acc2 += __shfl_xor(acc2, off);
        }
        if (lane == 0) {
            float gi_r = acc0 + b_ih[j];
            float gi_z = acc1 + b_ih[H + j];
            float gi_n = acc2 + b_ih[2 * H + j];
            float r = 1.f / (1.f + expf(-(gi_r + b_hh[j])));
            float z = 1.f / (1.f + expf(-(gi_z + b_hh[H + j])));
            float n = tanhf(gi_n + r * b_hh[2 * H + j]);
            float hnew = (1.f - z) * n;              // + z*h0, h0 = 0
            float outv = 1.f / (1.f + expf(-hnew));
            d_out[j] = outv;                         // out
            d_out[H + j] = hnew;                     // h_new
        }
    }
}

extern "C" void kernel_launch(void* const* d_in, const int* in_sizes, int n_in,
                              void* d_out, int out_size, void* d_ws, size_t ws_size,
                              hipStream_t stream) {
    const int*   inputId     = (const int*)d_in[0];
    const float* hidden      = (const float*)d_in[1];
    const float* enc         = (const float*)d_in[2];
    const float* embed_table = (const float*)d_in[3];
    const float* attn_w      = (const float*)d_in[4];
    const float* attn_b      = (const float*)d_in[5];
    const float* comb_w      = (const float*)d_in[6];
    const float* comb_b      = (const float*)d_in[7];
    const float* w_ih        = (const float*)d_in[8];
    // d_in[9] = w_hh is dead: h0 == 0 so gh = b_hh
    const float* b_ih        = (const float*)d_in[10];
    const float* b_hh        = (const float*)d_in[11];

    float* out = (float*)d_out;   // [0:1024) out, [1024:2048) h_new, [2048:2560) attnWeights
    char*  ws  = (char*)d_ws;

    // zero counters + release flags (deterministic across graph replays)
    hipMemsetAsync(d_ws, 0, 2304, stream);

    void* args[] = {
        (void*)&inputId, (void*)&hidden, (void*)&enc, (void*)&embed_table,
        (void*)&attn_w, (void*)&attn_b, (void*)&comb_w, (void*)&comb_b,
        (void*)&w_ih, (void*)&b_ih, (void*)&b_hh, (void*)&out, (void*)&ws
    };
    hipLaunchCooperativeKernel((const void*)fused_decoder, dim3(NB), dim3(NT),
                               args, 0, stream);
}

// Round 7
// 37.904 us; speedup vs baseline: 1.6202x; 1.6202x over previous
//
#include <hip/hip_runtime.h>
#include <hip/hip_bf16.h>

#define H 1024
#define MAXLEN 512

typedef __bf16 bf16x8 __attribute__((ext_vector_type(8)));
typedef __bf16 bf16x4 __attribute__((ext_vector_type(4)));
typedef float  f32x4  __attribute__((ext_vector_type(4)));

__device__ __forceinline__ float wave_reduce_sum(float a) {
    #pragma unroll
    for (int off = 32; off; off >>= 1) a += __shfl_xor(a, off);
    return a;
}
__device__ __forceinline__ float wave_reduce_max(float a) {
    #pragma unroll
    for (int off = 32; off; off >>= 1) a = fmaxf(a, __shfl_xor(a, off));
    return a;
}

// ws float layout: logits[512] @0 | y1[1024] @512 | z[1024] @1536 | Gt[1024*512] @2560
#define WS_LOGITS 0
#define WS_Y1     512
#define WS_Z      1536
#define WS_GT     2560
#define WS_FLOATS (2560 + 1024 * 512)

// ================= Node 1: logits || y1 || Gt = W2 @ enc^T (bf16 MFMA) =================
// grid 160 x 512: b<32 GEMM (8x4 tiles of 128x128), b in [32,96) logits, [96,160) y1
__global__ __launch_bounds__(512)
void node1(const int* __restrict__ inputId,
           const float* __restrict__ hidden,
           const float* __restrict__ enc,
           const float* __restrict__ embed_table,
           const float* __restrict__ attn_w,
           const float* __restrict__ attn_b,
           const float* __restrict__ comb_w,
           const float* __restrict__ comb_b,
           float* __restrict__ ws) {
    float* logits = ws + WS_LOGITS;
    float* y1     = ws + WS_Y1;
    float* Gt     = ws + WS_GT;

    __shared__ __bf16 lds_a[128][64];   // W2 tile rows (p), 64 k, slot-XOR swizzled
    __shared__ __bf16 lds_b[128][64];   // enc tile rows (q)

    const int tid  = threadIdx.x;
    const int lane = tid & 63;
    const int w    = tid >> 6;          // wave 0..7
    const int b    = blockIdx.x;

    const float* embed = embed_table + (size_t)inputId[0] * H;

    if (b < 32) {
        // Gt[p][q] = sum_r W2[p][r] * enc[q][r];  W2[p][r] = comb_w[p*2048 + 1024 + r]
        const int pBase = (b >> 2) * 128;
        const int qBase = (b & 3) * 128;
        const int wm = w & 3;           // row sub-tile: wm*32 .. +32
        const int wn = w >> 2;          // col sub-tile: wn*64 .. +64
        f32x4 acc[2][4];
        #pragma unroll
        for (int m = 0; m < 2; ++m)
            #pragma unroll
            for (int n = 0; n < 4; ++n) acc[m][n] = (f32x4){0.f, 0.f, 0.f, 0.f};

        for (int c = 0; c < 16; ++c) {  // 16 K-chunks of 64
            const int k0 = c * 64;
            #pragma unroll
            for (int i = 0; i < 4; ++i) {
                int f4  = tid + i * 512;        // 0..2047
                int row = f4 >> 4, c4 = f4 & 15;
                float4 ga = *(const float4*)(comb_w + (size_t)(pBase + row) * 2048 + 1024 + k0 + c4 * 4);
                float4 gb = *(const float4*)(enc    + (size_t)(qBase + row) * 1024 +        k0 + c4 * 4);
                // slot-XOR swizzle (T2): 16B slot s stored at s ^ (row&7)
                int off = ((((c4 >> 1) ^ (row & 7)) << 4) | ((c4 & 1) << 3));
                bf16x4 va, vb;
                va[0] = (__bf16)ga.x; va[1] = (__bf16)ga.y; va[2] = (__bf16)ga.z; va[3] = (__bf16)ga.w;
                vb[0] = (__bf16)gb.x; vb[1] = (__bf16)gb.y; vb[2] = (__bf16)gb.z; vb[3] = (__bf16)gb.w;
                *(bf16x4*)((char*)(&lds_a[row][0]) + off) = va;
                *(bf16x4*)((char*)(&lds_b[row][0]) + off) = vb;
            }
            __syncthreads();
            #pragma unroll
            for (int ks = 0; ks < 2; ++ks) {
                const int slot = ks * 4 + (lane >> 4);      // k-slot 0..7 (8 bf16 each)
                bf16x8 af[2], bfr[4];
                #pragma unroll
                for (int m = 0; m < 2; ++m) {
                    int row = wm * 32 + m * 16 + (lane & 15);
                    af[m] = *(const bf16x8*)((const char*)(&lds_a[row][0]) + ((slot ^ (row & 7)) << 4));
                }
                #pragma unroll
                for (int n = 0; n < 4; ++n) {
                    int row = wn * 64 + n * 16 + (lane & 15);
                    bfr[n] = *(const bf16x8*)((const char*)(&lds_b[row][0]) + ((slot ^ (row & 7)) << 4));
                }
                // A,B frags use the IDENTICAL lane->(row,k-slot) fill, so any hw
                // k-permutation applies to both operands -> dot invariant.
                #pragma unroll
                for (int m = 0; m < 2; ++m)
                    #pragma unroll
                    for (int n = 0; n < 4; ++n)
                        acc[m][n] = __builtin_amdgcn_mfma_f32_16x16x32_bf16(af[m], bfr[n], acc[m][n], 0, 0, 0);
            }
            __syncthreads();
        }
        // C/D layout (verified m89/m91): col = lane&15, row = (lane>>4)*4 + i
        #pragma unroll
        for (int m = 0; m < 2; ++m) {
            int p0 = pBase + wm * 32 + m * 16 + (lane >> 4) * 4;
            #pragma unroll
            for (int n = 0; n < 4; ++n) {
                int q = qBase + wn * 64 + n * 16 + (lane & 15);
                #pragma unroll
                for (int i = 0; i < 4; ++i)
                    Gt[(size_t)(p0 + i) * 512 + q] = acc[m][n][i];
            }
        }
    } else if (b < 96) {
        // logits[row] = attn_w[row,:].[embed|hidden] + attn_b[row]; 512 rows
        int row = (b - 32) * 8 + w;
        const float* wrow = attn_w + (size_t)row * (2 * H);
        float acc = 0.f;
        #pragma unroll
        for (int it = 0; it < 8; ++it) {
            int base = it * 256 + lane * 4;
            float4 wv = *(const float4*)(wrow + base);
            float4 cv = (it < 4) ? *(const float4*)(embed + base)
                                 : *(const float4*)(hidden + (base - H));
            acc += wv.x * cv.x + wv.y * cv.y + wv.z * cv.z + wv.w * cv.w;
        }
        acc = wave_reduce_sum(acc);
        if (lane == 0) logits[row] = acc + attn_b[row];
    } else {
        // y1[row] = W1[row,:].embed + comb_b[row]; 1024 rows
        #pragma unroll
        for (int rr = 0; rr < 2; ++rr) {
            int row = (b - 96) * 16 + w * 2 + rr;
            const float* wrow = comb_w + (size_t)row * (2 * H);
            float acc = 0.f;
            #pragma unroll
            for (int it = 0; it < 4; ++it) {
                int base = it * 256 + lane * 4;
                float4 wv = *(const float4*)(wrow + base);
                float4 ev = *(const float4*)(embed + base);
                acc += wv.x * ev.x + wv.y * ev.y + wv.z * ev.z + wv.w * ev.w;
            }
            acc = wave_reduce_sum(acc);
            if (lane == 0) y1[row] = acc + comb_b[row];
        }
    }
}

// ================= Node 2: softmax + z = y1 + Gt . w + attnWeights out =================
// 64 blocks x 256; block b owns z rows [b*16, b*16+16)
__global__ __launch_bounds__(256)
void node2(float* __restrict__ ws, float* __restrict__ d_out) {
    const float* logits = ws + WS_LOGITS;
    const float* y1     = ws + WS_Y1;
    const float* Gt     = ws + WS_GT;
    float* z = ws + WS_Z;

    __shared__ float wsm[MAXLEN];
    __shared__ float red[4];
    const int tid = threadIdx.x, lane = tid & 63, wid = tid >> 6;
    const int b = blockIdx.x;

    float l0 = logits[tid], l1 = logits[tid + 256];
    float m = wave_reduce_max(fmaxf(l0, l1));
    if (lane == 0) red[wid] = m;
    __syncthreads();
    m = fmaxf(fmaxf(red[0], red[1]), fmaxf(red[2], red[3]));
    __syncthreads();
    float e0 = expf(l0 - m), e1 = expf(l1 - m);
    float s = wave_reduce_sum(e0 + e1);
    if (lane == 0) red[wid] = s;
    __syncthreads();
    s = red[0] + red[1] + red[2] + red[3];
    float inv = 1.f / s;
    float w0 = e0 * inv, w1 = e1 * inv;
    wsm[tid] = w0;
    wsm[tid + 256] = w1;
    if (b == 0) {                       // attnWeights output (exact fp32)
        d_out[2048 + tid] = w0;
        d_out[2048 + 256 + tid] = w1;
    }
    __syncthreads();

    #pragma unroll
    for (int rr = 0; rr < 4; ++rr) {
        int row = b * 16 + wid * 4 + rr;            // 0..1023
        const float* g = Gt + (size_t)row * 512;
        float acc = 0.f;
        #pragma unroll
        for (int i = 0; i < 8; ++i)
            acc += g[lane + 64 * i] * wsm[lane + 64 * i];
        acc = wave_reduce_sum(acc);
        if (lane == 0) z[row] = y1[row] + acc;
    }
}

// ================= Node 3: GRU (x = relu(z) inline; h0 = 0 -> gh = b_hh) =================
__global__ __launch_bounds__(256)
void node3(const float* __restrict__ w_ih,
           const float* __restrict__ b_ih,
           const float* __restrict__ b_hh,
           const float* __restrict__ ws,
           float* __restrict__ d_out) {
    const float* z = ws + WS_Z;
    int lane = threadIdx.x & 63;
    int j = blockIdx.x * 4 + (threadIdx.x >> 6);    // 0..1023
    float acc0 = 0.f, acc1 = 0.f, acc2 = 0.f;
    const float* wr = w_ih + (size_t)j * H;
    const float* wz = w_ih + (size_t)(H + j) * H;
    const float* wn = w_ih + (size_t)(2 * H + j) * H;
    #pragma unroll
    for (int it = 0; it < 4; ++it) {
        int base = it * 256 + lane * 4;
        float4 xv = *(const float4*)(z + base);
        xv.x = fmaxf(xv.x, 0.f); xv.y = fmaxf(xv.y, 0.f);
        xv.z = fmaxf(xv.z, 0.f); xv.w = fmaxf(xv.w, 0.f);
        float4 a = *(const float4*)(wr + base);
        float4 c = *(const float4*)(wz + base);
        float4 d = *(const float4*)(wn + base);
        acc0 += a.x * xv.x + a.y * xv.y + a.z * xv.z + a.w * xv.w;
        acc1 += c.x * xv.x + c.y * xv.y + c.z * xv.z + c.w * xv.w;
        acc2 += d.x * xv.x + d.y * xv.y + d.z * xv.z + d.w * xv.w;
    }
    #pragma unroll
    for (int off = 32; off; off >>= 1) {
        acc0 += __shfl_xor(acc0, off);
        acc1 += __shfl_xor(acc1, off);
        acc2 += __shfl_xor(acc2, off);
    }
    if (lane == 0) {
        float gi_r = acc0 + b_ih[j];
        float gi_z = acc1 + b_ih[H + j];
        float gi_n = acc2 + b_ih[2 * H + j];
        float r = 1.f / (1.f + expf(-(gi_r + b_hh[j])));
        float zz = 1.f / (1.f + expf(-(gi_z + b_hh[H + j])));
        float n = tanhf(gi_n + r * b_hh[2 * H + j]);
        float hnew = (1.f - zz) * n;                // + z*h0, h0 = 0
        float outv = 1.f / (1.f + expf(-hnew));
        d_out[j] = outv;
        d_out[H + j] = hnew;
    }
}

// ================= Fallback (R2-proven 4-kernel path, used if ws too small) =================
__global__ void fb_kA(const int* __restrict__ inputId, const float* __restrict__ embed_table,
                      const float* __restrict__ hidden, const float* __restrict__ attn_w,
                      const float* __restrict__ attn_b, float* __restrict__ logits) {
    int lane = threadIdx.x & 63;
    int row = blockIdx.x * 4 + (threadIdx.x >> 6);
    const float* embed = embed_table + (size_t)inputId[0] * H;
    const float* wrow = attn_w + (size_t)row * (2 * H);
    float acc = 0.f;
    #pragma unroll
    for (int it = 0; it < 8; ++it) {
        int base = it * 256 + lane * 4;
        float4 wv = *(const float4*)(wrow + base);
        float4 cv = (it < 4) ? *(const float4*)(embed + base)
                             : *(const float4*)(hidden + (base - H));
        acc += wv.x * cv.x + wv.y * cv.y + wv.z * cv.z + wv.w * cv.w;
    }
    acc = wave_reduce_sum(acc);
    if (lane == 0) logits[row] = acc + attn_b[row];
}
__global__ void fb_kB(const float* __restrict__ logits, const float* __restrict__ enc,
                      float* __restrict__ attnApplied, float* __restrict__ out_w) {
    __shared__ float w_lds[MAXLEN];
    __shared__ float red[4];
    __shared__ float part[8][32];
    int tid = threadIdx.x, lane = tid & 63, wid = tid >> 6;
    float l0 = logits[tid], l1 = logits[tid + 256];
    float m = wave_reduce_max(fmaxf(l0, l1));
    if (lane == 0) red[wid] = m;
    __syncthreads();
    m = fmaxf(fmaxf(red[0], red[1]), fmaxf(red[2], red[3]));
    __syncthreads();
    float e0 = expf(l0 - m), e1 = expf(l1 - m);
    float s = wave_reduce_sum(e0 + e1);
    if (lane == 0) red[wid] = s;
    __syncthreads();
    s = red[0] + red[1] + red[2] + red[3];
    float inv = 1.f / s;
    float w0 = e0 * inv, w1 = e1 * inv;
    w_lds[tid] = w0; w_lds[tid + 256] = w1;
    if (blockIdx.x == 0) { out_w[tid] = w0; out_w[tid + 256] = w1; }
    __syncthreads();
    int c = tid & 31, ks = tid >> 5;
    int col = blockIdx.x * 32 + c;
    float acc = 0.f;
    for (int k = ks; k < MAXLEN; k += 8) acc += w_lds[k] * enc[(size_t)k * H + col];
    part[ks][c] = acc;
    __syncthreads();
    if (tid < 32) {
        float t = 0.f;
        #pragma unroll
        for (int i = 0; i < 8; ++i) t += part[i][tid];
        attnApplied[blockIdx.x * 32 + tid] = t;
    }
}
__global__ void fb_kC(const int* __restrict__ inputId, const float* __restrict__ embed_table,
                      const float* __restrict__ attnApplied, const float* __restrict__ comb_w,
                      const float* __restrict__ comb_b, float* __restrict__ x) {
    int lane = threadIdx.x & 63;
    int row = blockIdx.x * 4 + (threadIdx.x >> 6);
    const float* embed = embed_table + (size_t)inputId[0] * H;
    const float* wrow = comb_w + (size_t)row * (2 * H);
    float acc = 0.f;
    #pragma unroll
    for (int it = 0; it < 8; ++it) {
        int base = it * 256 + lane * 4;
        float4 wv = *(const float4*)(wrow + base);
        float4 cv = (it < 4) ? *(const float4*)(embed + base)
                             : *(const float4*)(attnApplied + (base - H));
        acc += wv.x * cv.x + wv.y * cv.y + wv.z * cv.z + wv.w * cv.w;
    }
    acc = wave_reduce_sum(acc);
    if (lane == 0) x[row] = fmaxf(acc + comb_b[row], 0.f);
}
__global__ void fb_kD(const float* __restrict__ w_ih, const float* __restrict__ b_ih,
                      const float* __restrict__ b_hh, const float* __restrict__ x,
                      float* __restrict__ d_out) {
    int lane = threadIdx.x & 63;
    int j = blockIdx.x * 4 + (threadIdx.x >> 6);
    float acc0 = 0.f, acc1 = 0.f, acc2 = 0.f;
    const float* wr = w_ih + (size_t)j * H;
    const float* wz = w_ih + (size_t)(H + j) * H;
    const float* wn = w_ih + (size_t)(2 * H + j) * H;
    #pragma unroll
    for (int it = 0; it < 4; ++it) {
        int base = it * 256 + lane * 4;
        float4 xv = *(const float4*)(x + base);
        float4 a = *(const float4*)(wr + base);
        float4 c = *(const float4*)(wz + base);
        float4 d = *(const float4*)(wn + base);
        acc0 += a.x * xv.x + a.y * xv.y + a.z * xv.z + a.w * xv.w;
        acc1 += c.x * xv.x + c.y * xv.y + c.z * xv.z + c.w * xv.w;
        acc2 += d.x * xv.x + d.y * xv.y + d.z * xv.z + d.w * xv.w;
    }
    #pragma unroll
    for (int off = 32; off; off >>= 1) {
        acc0 += __shfl_xor(acc0, off);
        acc1 += __shfl_xor(acc1, off);
        acc2 += __shfl_xor(acc2, off);
    }
    if (lane == 0) {
        float gi_r = acc0 + b_ih[j];
        float gi_z = acc1 + b_ih[H + j];
        float gi_n = acc2 + b_ih[2 * H + j];
        float r = 1.f / (1.f + expf(-(gi_r + b_hh[j])));
        float z = 1.f / (1.f + expf(-(gi_z + b_hh[H + j])));
        float n = tanhf(gi_n + r * b_hh[2 * H + j]);
        float hnew = (1.f - z) * n;
        float outv = 1.f / (1.f + expf(-hnew));
        d_out[j] = outv;
        d_out[H + j] = hnew;
    }
}

extern "C" void kernel_launch(void* const* d_in, const int* in_sizes, int n_in,
                              void* d_out, int out_size, void* d_ws, size_t ws_size,
                              hipStream_t stream) {
    const int*   inputId     = (const int*)d_in[0];
    const float* hidden      = (const float*)d_in[1];
    const float* enc         = (const float*)d_in[2];
    const float* embed_table = (const float*)d_in[3];
    const float* attn_w      = (const float*)d_in[4];
    const float* attn_b      = (const float*)d_in[5];
    const float* comb_w      = (const float*)d_in[6];
    const float* comb_b      = (const float*)d_in[7];
    const float* w_ih        = (const float*)d_in[8];
    // d_in[9] = w_hh dead: h0 == 0 -> gh = b_hh
    const float* b_ih        = (const float*)d_in[10];
    const float* b_hh        = (const float*)d_in[11];

    float* out = (float*)d_out;   // [0:1024) out, [1024:2048) h_new, [2048:2560) attnWeights
    float* ws  = (float*)d_ws;

    if (ws_size >= (size_t)WS_FLOATS * sizeof(float)) {
        node1<<<160, 512, 0, stream>>>(inputId, hidden, enc, embed_table,
                                       attn_w, attn_b, comb_w, comb_b, ws);
        node2<<<64, 256, 0, stream>>>(ws, out);
        node3<<<256, 256, 0, stream>>>(w_ih, b_ih, b_hh, ws, out);
    } else {
        float* logits      = ws;
        float* attnApplied = ws + 512;
        float* x           = ws + 2048;
        fb_kA<<<128, 256, 0, stream>>>(inputId, embed_table, hidden, attn_w, attn_b, logits);
        fb_kB<<<32,  256, 0, stream>>>(logits, enc, attnApplied, out + 2048);
        fb_kC<<<256, 256, 0, stream>>>(inputId, embed_table, attnApplied, comb_w, comb_b, x);
        fb_kD<<<256, 256, 0, stream>>>(w_ih, b_ih, b_hh, x, out);
    }
}

// Round 8
// 32.885 us; speedup vs baseline: 1.8675x; 1.1526x over previous
//
#include <hip/hip_runtime.h>
#include <hip/hip_bf16.h>

#define H 1024
#define MAXLEN 512

typedef __bf16 bf16x8 __attribute__((ext_vector_type(8)));
typedef __bf16 bf16x4 __attribute__((ext_vector_type(4)));
typedef float  f32x4  __attribute__((ext_vector_type(4)));

__device__ __forceinline__ float wave_reduce_sum(float a) {
    #pragma unroll
    for (int off = 32; off; off >>= 1) a += __shfl_xor(a, off);
    return a;
}
__device__ __forceinline__ float wave_reduce_max(float a) {
    #pragma unroll
    for (int off = 32; off; off >>= 1) a = fmaxf(a, __shfl_xor(a, off));
    return a;
}

// ws float layout: logits[512] @0 | x[1024] @512 | Gt[1024*512] @2048
#define WS_LOGITS 0
#define WS_X      512
#define WS_GT     2048
#define WS_FLOATS (2048 + 1024 * 512)

// ================= Node 1: Gt = W2 @ enc^T (bf16 MFMA, pipelined) || logits =================
// 128 blocks x 512: b<64 GEMM (8p x 8q tiles of 128x64), b in [64,128) logits.
__global__ __launch_bounds__(512)
void node1(const int* __restrict__ inputId,
           const float* __restrict__ hidden,
           const float* __restrict__ enc,
           const float* __restrict__ embed_table,
           const float* __restrict__ attn_w,
           const float* __restrict__ attn_b,
           const float* __restrict__ comb_w,
           float* __restrict__ ws) {
    float* logits = ws + WS_LOGITS;
    float* Gt     = ws + WS_GT;

    // double-buffered LDS, slot-XOR swizzled (16B slot s at s^(row&7))
    __shared__ __bf16 Asm[2][128][64];   // W2 tile (p rows), 32 KB
    __shared__ __bf16 Bsm[2][64][64];    // enc tile (q rows), 16 KB

    const int tid  = threadIdx.x;
    const int lane = tid & 63;
    const int w    = tid >> 6;           // wave 0..7
    const int b    = blockIdx.x;

    if (b < 64) {
        const int pBase = (b >> 3) * 128;
        const int qBase = (b & 7) * 64;
        const int wp = w >> 1;           // 0..3 : rows wp*32..+32
        const int wq = w & 1;            // 0..1 : cols wq*32..+32

        // staging coords (constant per thread)
        const int arow0 = tid >> 4,  ac4 = tid & 15;          // A: 4 iters, rows +32 apart
        const int aoff  = (((ac4 >> 1) ^ 0) << 4) | ((ac4 & 1) << 3); // row-XOR applied below
        (void)aoff;

        f32x4 acc[2][2];
        #pragma unroll
        for (int m = 0; m < 2; ++m)
            #pragma unroll
            for (int n = 0; n < 2; ++n) acc[m][n] = (f32x4){0.f, 0.f, 0.f, 0.f};

        float4 ra[4], rb[2];

        auto loadChunk = [&](int k0) {
            #pragma unroll
            for (int i = 0; i < 4; ++i) {
                int row = arow0 + i * 32;
                ra[i] = *(const float4*)(comb_w + (size_t)(pBase + row) * 2048 + 1024 + k0 + ac4 * 4);
            }
            #pragma unroll
            for (int i = 0; i < 2; ++i) {
                int row = arow0 + i * 32;
                rb[i] = *(const float4*)(enc + (size_t)(qBase + row) * 1024 + k0 + ac4 * 4);
            }
        };
        auto writeChunk = [&](int buf) {
            #pragma unroll
            for (int i = 0; i < 4; ++i) {
                int row = arow0 + i * 32;
                int off = ((((ac4 >> 1) ^ (row & 7)) << 4) | ((ac4 & 1) << 3));
                bf16x4 v;
                v[0] = (__bf16)ra[i].x; v[1] = (__bf16)ra[i].y;
                v[2] = (__bf16)ra[i].z; v[3] = (__bf16)ra[i].w;
                *(bf16x4*)((char*)(&Asm[buf][row][0]) + off) = v;
            }
            #pragma unroll
            for (int i = 0; i < 2; ++i) {
                int row = arow0 + i * 32;
                int off = ((((ac4 >> 1) ^ (row & 7)) << 4) | ((ac4 & 1) << 3));
                bf16x4 v;
                v[0] = (__bf16)rb[i].x; v[1] = (__bf16)rb[i].y;
                v[2] = (__bf16)rb[i].z; v[3] = (__bf16)rb[i].w;
                *(bf16x4*)((char*)(&Bsm[buf][row][0]) + off) = v;
            }
        };

        // prologue: chunk 0 -> buf 0
        loadChunk(0);
        writeChunk(0);
        __syncthreads();

        for (int c = 0; c < 16; ++c) {
            const int cur = c & 1;
            if (c < 15) loadChunk((c + 1) * 64);      // issue early (in flight during MFMA)
            #pragma unroll
            for (int ks = 0; ks < 2; ++ks) {
                const int slot = ks * 4 + (lane >> 4);
                bf16x8 af[2], bfv[2];
                #pragma unroll
                for (int m = 0; m < 2; ++m) {
                    int row = wp * 32 + m * 16 + (lane & 15);
                    af[m] = *(const bf16x8*)((const char*)(&Asm[cur][row][0]) + ((slot ^ (row & 7)) << 4));
                }
                #pragma unroll
                for (int n = 0; n < 2; ++n) {
                    int row = wq * 32 + n * 16 + (lane & 15);
                    bfv[n] = *(const bf16x8*)((const char*)(&Bsm[cur][row][0]) + ((slot ^ (row & 7)) << 4));
                }
                // A,B frags use IDENTICAL lane->(row,k-slot) fill: any hw k-permutation
                // hits both operands -> dot invariant (numerics proven R7).
                #pragma unroll
                for (int m = 0; m < 2; ++m)
                    #pragma unroll
                    for (int n = 0; n < 2; ++n)
                        acc[m][n] = __builtin_amdgcn_mfma_f32_16x16x32_bf16(af[m], bfv[n], acc[m][n], 0, 0, 0);
            }
            if (c < 15) writeChunk(cur ^ 1);           // write-late (vmcnt waits here, not at MFMA)
            __syncthreads();
        }

        // C/D layout (m89-verified): col = lane&15, row = (lane>>4)*4 + i
        #pragma unroll
        for (int m = 0; m < 2; ++m) {
            int p0 = pBase + wp * 32 + m * 16 + (lane >> 4) * 4;
            #pragma unroll
            for (int n = 0; n < 2; ++n) {
                int q = qBase + wq * 32 + n * 16 + (lane & 15);
                #pragma unroll
                for (int i = 0; i < 4; ++i)
                    Gt[(size_t)(p0 + i) * 512 + q] = acc[m][n][i];
            }
        }
    } else {
        // logits[row] = attn_w[row,:].[embed|hidden] + attn_b[row]; 512 rows, 1/wave
        const float* embed = embed_table + (size_t)inputId[0] * H;
        int row = (b - 64) * 8 + w;
        const float* wrow = attn_w + (size_t)row * (2 * H);
        float acc = 0.f;
        #pragma unroll
        for (int it = 0; it < 8; ++it) {
            int base = it * 256 + lane * 4;
            float4 wv = *(const float4*)(wrow + base);
            float4 cv = (it < 4) ? *(const float4*)(embed + base)
                                 : *(const float4*)(hidden + (base - H));
            acc += wv.x * cv.x + wv.y * cv.y + wv.z * cv.z + wv.w * cv.w;
        }
        acc = wave_reduce_sum(acc);
        if (lane == 0) logits[row] = acc + attn_b[row];
    }
}

// ================= Node 2: softmax + x = relu(W1.embed + Gt.w + comb_b) =================
// 128 blocks x 256; block b owns x rows [b*8, b*8+8) (2 rows/wave).
__global__ __launch_bounds__(256)
void node2(const int* __restrict__ inputId,
           const float* __restrict__ embed_table,
           const float* __restrict__ comb_w,
           const float* __restrict__ comb_b,
           float* __restrict__ ws,
           float* __restrict__ d_out) {
    const float* logits = ws + WS_LOGITS;
    const float* Gt     = ws + WS_GT;
    float* x = ws + WS_X;

    __shared__ float wsm[MAXLEN];
    __shared__ float red[4];
    const int tid = threadIdx.x, lane = tid & 63, wid = tid >> 6;
    const int b = blockIdx.x;

    float l0 = logits[tid], l1 = logits[tid + 256];
    float m = wave_reduce_max(fmaxf(l0, l1));
    if (lane == 0) red[wid] = m;
    __syncthreads();
    m = fmaxf(fmaxf(red[0], red[1]), fmaxf(red[2], red[3]));
    __syncthreads();
    float e0 = expf(l0 - m), e1 = expf(l1 - m);
    float s = wave_reduce_sum(e0 + e1);
    if (lane == 0) red[wid] = s;
    __syncthreads();
    s = red[0] + red[1] + red[2] + red[3];
    float inv = 1.f / s;
    float w0 = e0 * inv, w1 = e1 * inv;
    wsm[tid] = w0;
    wsm[tid + 256] = w1;
    if (b == 0) {                        // attnWeights (exact fp32)
        d_out[2048 + tid] = w0;
        d_out[2048 + 256 + tid] = w1;
    }
    __syncthreads();

    const float* embed = embed_table + (size_t)inputId[0] * H;
    #pragma unroll
    for (int rr = 0; rr < 2; ++rr) {
        int row = b * 8 + wid * 2 + rr;                 // 0..1023
        const float* w1row = comb_w + (size_t)row * (2 * H);   // W1 half
        float acc = 0.f;
        #pragma unroll
        for (int it = 0; it < 4; ++it) {
            int base = it * 256 + lane * 4;
            float4 wv = *(const float4*)(w1row + base);
            float4 ev = *(const float4*)(embed + base);
            acc += wv.x * ev.x + wv.y * ev.y + wv.z * ev.z + wv.w * ev.w;
        }
        const float* g = Gt + (size_t)row * 512;
        #pragma unroll
        for (int i = 0; i < 8; ++i)
            acc += g[lane + 64 * i] * wsm[lane + 64 * i];
        acc = wave_reduce_sum(acc);
        if (lane == 0) x[row] = fmaxf(acc + comb_b[row], 0.f);
    }
}

// ================= Node 3: GRU (h0 = 0 -> gh = b_hh) =================
__global__ __launch_bounds__(256)
void node3(const float* __restrict__ w_ih,
           const float* __restrict__ b_ih,
           const float* __restrict__ b_hh,
           const float* __restrict__ ws,
           float* __restrict__ d_out) {
    const float* x = ws + WS_X;
    int lane = threadIdx.x & 63;
    int j = blockIdx.x * 4 + (threadIdx.x >> 6);        // 0..1023
    float acc0 = 0.f, acc1 = 0.f, acc2 = 0.f;
    const float* wr = w_ih + (size_t)j * H;
    const float* wz = w_ih + (size_t)(H + j) * H;
    const float* wn = w_ih + (size_t)(2 * H + j) * H;
    #pragma unroll
    for (int it = 0; it < 4; ++it) {
        int base = it * 256 + lane * 4;
        float4 xv = *(const float4*)(x + base);
        float4 a = *(const float4*)(wr + base);
        float4 c = *(const float4*)(wz + base);
        float4 d = *(const float4*)(wn + base);
        acc0 += a.x * xv.x + a.y * xv.y + a.z * xv.z + a.w * xv.w;
        acc1 += c.x * xv.x + c.y * xv.y + c.z * xv.z + c.w * xv.w;
        acc2 += d.x * xv.x + d.y * xv.y + d.z * xv.z + d.w * xv.w;
    }
    #pragma unroll
    for (int off = 32; off; off >>= 1) {
        acc0 += __shfl_xor(acc0, off);
        acc1 += __shfl_xor(acc1, off);
        acc2 += __shfl_xor(acc2, off);
    }
    if (lane == 0) {
        float gi_r = acc0 + b_ih[j];
        float gi_z = acc1 + b_ih[H + j];
        float gi_n = acc2 + b_ih[2 * H + j];
        float r = 1.f / (1.f + expf(-(gi_r + b_hh[j])));
        float zz = 1.f / (1.f + expf(-(gi_z + b_hh[H + j])));
        float n = tanhf(gi_n + r * b_hh[2 * H + j]);
        float hnew = (1.f - zz) * n;                    // + z*h0, h0 = 0
        float outv = 1.f / (1.f + expf(-hnew));
        d_out[j] = outv;
        d_out[H + j] = hnew;
    }
}

// ================= Fallback (R2-proven 4-kernel path, used if ws too small) =================
__global__ void fb_kA(const int* __restrict__ inputId, const float* __restrict__ embed_table,
                      const float* __restrict__ hidden, const float* __restrict__ attn_w,
                      const float* __restrict__ attn_b, float* __restrict__ logits) {
    int lane = threadIdx.x & 63;
    int row = blockIdx.x * 4 + (threadIdx.x >> 6);
    const float* embed = embed_table + (size_t)inputId[0] * H;
    const float* wrow = attn_w + (size_t)row * (2 * H);
    float acc = 0.f;
    #pragma unroll
    for (int it = 0; it < 8; ++it) {
        int base = it * 256 + lane * 4;
        float4 wv = *(const float4*)(wrow + base);
        float4 cv = (it < 4) ? *(const float4*)(embed + base)
                             : *(const float4*)(hidden + (base - H));
        acc += wv.x * cv.x + wv.y * cv.y + wv.z * cv.z + wv.w * cv.w;
    }
    acc = wave_reduce_sum(acc);
    if (lane == 0) logits[row] = acc + attn_b[row];
}
__global__ void fb_kB(const float* __restrict__ logits, const float* __restrict__ enc,
                      float* __restrict__ attnApplied, float* __restrict__ out_w) {
    __shared__ float w_lds[MAXLEN];
    __shared__ float red[4];
    __shared__ float part[8][32];
    int tid = threadIdx.x, lane = tid & 63, wid = tid >> 6;
    float l0 = logits[tid], l1 = logits[tid + 256];
    float m = wave_reduce_max(fmaxf(l0, l1));
    if (lane == 0) red[wid] = m;
    __syncthreads();
    m = fmaxf(fmaxf(red[0], red[1]), fmaxf(red[2], red[3]));
    __syncthreads();
    float e0 = expf(l0 - m), e1 = expf(l1 - m);
    float s = wave_reduce_sum(e0 + e1);
    if (lane == 0) red[wid] = s;
    __syncthreads();
    s = red[0] + red[1] + red[2] + red[3];
    float inv = 1.f / s;
    float w0 = e0 * inv, w1 = e1 * inv;
    w_lds[tid] = w0; w_lds[tid + 256] = w1;
    if (blockIdx.x == 0) { out_w[tid] = w0; out_w[tid + 256] = w1; }
    __syncthreads();
    int c = tid & 31, ks = tid >> 5;
    int col = blockIdx.x * 32 + c;
    float acc = 0.f;
    for (int k = ks; k < MAXLEN; k += 8) acc += w_lds[k] * enc[(size_t)k * H + col];
    part[ks][c] = acc;
    __syncthreads();
    if (tid < 32) {
        float t = 0.f;
        #pragma unroll
        for (int i = 0; i < 8; ++i) t += part[i][tid];
        attnApplied[blockIdx.x * 32 + tid] = t;
    }
}
__global__ void fb_kC(const int* __restrict__ inputId, const float* __restrict__ embed_table,
                      const float* __restrict__ attnApplied, const float* __restrict__ comb_w,
                      const float* __restrict__ comb_b, float* __restrict__ x) {
    int lane = threadIdx.x & 63;
    int row = blockIdx.x * 4 + (threadIdx.x >> 6);
    const float* embed = embed_table + (size_t)inputId[0] * H;
    const float* wrow = comb_w + (size_t)row * (2 * H);
    float acc = 0.f;
    #pragma unroll
    for (int it = 0; it < 8; ++it) {
        int base = it * 256 + lane * 4;
        float4 wv = *(const float4*)(wrow + base);
        float4 cv = (it < 4) ? *(const float4*)(embed + base)
                             : *(const float4*)(attnApplied + (base - H));
        acc += wv.x * cv.x + wv.y * cv.y + wv.z * cv.z + wv.w * cv.w;
    }
    acc = wave_reduce_sum(acc);
    if (lane == 0) x[row] = fmaxf(acc + comb_b[row], 0.f);
}
__global__ void fb_kD(const float* __restrict__ w_ih, const float* __restrict__ b_ih,
                      const float* __restrict__ b_hh, const float* __restrict__ x,
                      float* __restrict__ d_out) {
    int lane = threadIdx.x & 63;
    int j = blockIdx.x * 4 + (threadIdx.x >> 6);
    float acc0 = 0.f, acc1 = 0.f, acc2 = 0.f;
    const float* wr = w_ih + (size_t)j * H;
    const float* wz = w_ih + (size_t)(H + j) * H;
    const float* wn = w_ih + (size_t)(2 * H + j) * H;
    #pragma unroll
    for (int it = 0; it < 4; ++it) {
        int base = it * 256 + lane * 4;
        float4 xv = *(const float4*)(x + base);
        float4 a = *(const float4*)(wr + base);
        float4 c = *(const float4*)(wz + base);
        float4 d = *(const float4*)(wn + base);
        acc0 += a.x * xv.x + a.y * xv.y + a.z * xv.z + a.w * xv.w;
        acc1 += c.x * xv.x + c.y * xv.y + c.z * xv.z + c.w * xv.w;
        acc2 += d.x * xv.x + d.y * xv.y + d.z * xv.z + d.w * xv.w;
    }
    #pragma unroll
    for (int off = 32; off; off >>= 1) {
        acc0 += __shfl_xor(acc0, off);
        acc1 += __shfl_xor(acc1, off);
        acc2 += __shfl_xor(acc2, off);
    }
    if (lane == 0) {
        float gi_r = acc0 + b_ih[j];
        float gi_z = acc1 + b_ih[H + j];
        float gi_n = acc2 + b_ih[2 * H + j];
        float r = 1.f / (1.f + expf(-(gi_r + b_hh[j])));
        float z = 1.f / (1.f + expf(-(gi_z + b_hh[H + j])));
        float n = tanhf(gi_n + r * b_hh[2 * H + j]);
        float hnew = (1.f - z) * n;
        float outv = 1.f / (1.f + expf(-hnew));
        d_out[j] = outv;
        d_out[H + j] = hnew;
    }
}

extern "C" void kernel_launch(void* const* d_in, const int* in_sizes, int n_in,
                              void* d_out, int out_size, void* d_ws, size_t ws_size,
                              hipStream_t stream) {
    const int*   inputId     = (const int*)d_in[0];
    const float* hidden      = (const float*)d_in[1];
    const float* enc         = (const float*)d_in[2];
    const float* embed_table = (const float*)d_in[3];
    const float* attn_w      = (const float*)d_in[4];
    const float* attn_b      = (const float*)d_in[5];
    const float* comb_w      = (const float*)d_in[6];
    const float* comb_b      = (const float*)d_in[7];
    const float* w_ih        = (const float*)d_in[8];
    // d_in[9] = w_hh dead: h0 == 0 -> gh = b_hh
    const float* b_ih        = (const float*)d_in[10];
    const float* b_hh        = (const float*)d_in[11];

    float* out = (float*)d_out;   // [0:1024) out, [1024:2048) h_new, [2048:2560) attnWeights
    float* ws  = (float*)d_ws;

    if (ws_size >= (size_t)WS_FLOATS * sizeof(float)) {
        node1<<<128, 512, 0, stream>>>(inputId, hidden, enc, embed_table,
                                       attn_w, attn_b, comb_w, ws);
        node2<<<128, 256, 0, stream>>>(inputId, embed_table, comb_w, comb_b, ws, out);
        node3<<<256, 256, 0, stream>>>(w_ih, b_ih, b_hh, ws, out);
    } else {
        float* logits      = ws;
        float* attnApplied = ws + 512;
        float* x           = ws + 2048;
        fb_kA<<<128, 256, 0, stream>>>(inputId, embed_table, hidden, attn_w, attn_b, logits);
        fb_kB<<<32,  256, 0, stream>>>(logits, enc, attnApplied, out + 2048);
        fb_kC<<<256, 256, 0, stream>>>(inputId, embed_table, attnApplied, comb_w, comb_b, x);
        fb_kD<<<256, 256, 0, stream>>>(w_ih, b_ih, b_hh, x, out);
    }
}

// Round 9
// 24.711 us; speedup vs baseline: 2.4851x; 1.3307x over previous
//
#include <hip/hip_runtime.h>
#include <hip/hip_bf16.h>

#define H 1024
#define MAXLEN 512

typedef __bf16 bf16x8 __attribute__((ext_vector_type(8)));
typedef __bf16 bf16x4 __attribute__((ext_vector_type(4)));
typedef float  f32x4  __attribute__((ext_vector_type(4)));

__device__ __forceinline__ float wave_reduce_sum(float a) {
    #pragma unroll
    for (int off = 32; off; off >>= 1) a += __shfl_xor(a, off);
    return a;
}
__device__ __forceinline__ float wave_reduce_max(float a) {
    #pragma unroll
    for (int off = 32; off; off >>= 1) a = fmaxf(a, __shfl_xor(a, off));
    return a;
}

// ws float layout: logits[512] @0 | x[1024] @512 | y1[1024] @2048 | Gt0 @4096 | Gt1 @4096+512K
#define WS_LOGITS 0
#define WS_X      512
#define WS_Y1     2048
#define WS_GT     4096
#define GT_HALF   (1024 * 512)
#define WS_FLOATS (4096 + 2 * GT_HALF)

// ================= Node 1: Gt = W2 @ enc^T (bf16 MFMA, split-K, XCD-grouped) || logits || y1
// 256 blocks x 512:
//   b in [0,128):  GEMM. p = b&7 (XCD-grouped A-panel), q = (b>>3)&7, kh = b>>6.
//   b in [128,192): logits (512 rows, 1/wave)
//   b in [192,256): y1 (1024 rows, 2/wave)
__global__ __launch_bounds__(512)
void node1(const int* __restrict__ inputId,
           const float* __restrict__ hidden,
           const float* __restrict__ enc,
           const float* __restrict__ embed_table,
           const float* __restrict__ attn_w,
           const float* __restrict__ attn_b,
           const float* __restrict__ comb_w,
           const float* __restrict__ comb_b,
           float* __restrict__ ws) {
    float* logits = ws + WS_LOGITS;
    float* y1     = ws + WS_Y1;

    __shared__ __bf16 Asm[2][128][64];   // 32 KB, slot-XOR swizzled
    __shared__ __bf16 Bsm[2][64][64];    // 16 KB

    const int tid  = threadIdx.x;
    const int lane = tid & 63;
    const int w    = tid >> 6;           // wave 0..7
    const int b    = blockIdx.x;

    if (b < 128) {
        const int pBase = (b & 7) * 128;         // XCD-grouped: same p -> same XCD
        const int qBase = ((b >> 3) & 7) * 64;
        const int kh    = b >> 6;                // split-K half
        const int kBase = kh * 512;
        float* GtH = ws + WS_GT + (size_t)kh * GT_HALF;

        const int wp = w >> 1;           // 0..3
        const int wq = w & 1;            // 0..1
        const int row16 = tid >> 4, c4 = tid & 15;

        f32x4 acc[2][2];
        #pragma unroll
        for (int m = 0; m < 2; ++m)
            #pragma unroll
            for (int n = 0; n < 2; ++n) acc[m][n] = (f32x4){0.f, 0.f, 0.f, 0.f};

        float4 ra[4], rb[2];
        auto loadChunk = [&](int c) {
            const int k0 = kBase + c * 64;
            #pragma unroll
            for (int i = 0; i < 4; ++i)
                ra[i] = *(const float4*)(comb_w + (size_t)(pBase + row16 + i * 32) * 2048 + 1024 + k0 + c4 * 4);
            #pragma unroll
            for (int i = 0; i < 2; ++i)
                rb[i] = *(const float4*)(enc + (size_t)(qBase + row16 + i * 32) * 1024 + k0 + c4 * 4);
        };
        auto writeChunk = [&](int buf) {
            #pragma unroll
            for (int i = 0; i < 4; ++i) {
                int row = row16 + i * 32;
                int off = ((((c4 >> 1) ^ (row & 7)) << 4) | ((c4 & 1) << 3));
                bf16x4 v;
                v[0] = (__bf16)ra[i].x; v[1] = (__bf16)ra[i].y;
                v[2] = (__bf16)ra[i].z; v[3] = (__bf16)ra[i].w;
                *(bf16x4*)((char*)(&Asm[buf][row][0]) + off) = v;
            }
            #pragma unroll
            for (int i = 0; i < 2; ++i) {
                int row = row16 + i * 32;
                int off = ((((c4 >> 1) ^ (row & 7)) << 4) | ((c4 & 1) << 3));
                bf16x4 v;
                v[0] = (__bf16)rb[i].x; v[1] = (__bf16)rb[i].y;
                v[2] = (__bf16)rb[i].z; v[3] = (__bf16)rb[i].w;
                *(bf16x4*)((char*)(&Bsm[buf][row][0]) + off) = v;
            }
        };

        loadChunk(0);
        writeChunk(0);
        __syncthreads();

        for (int c = 0; c < 8; ++c) {
            const int cur = c & 1;
            if (c < 7) loadChunk(c + 1);          // in flight during MFMA
            #pragma unroll
            for (int ks = 0; ks < 2; ++ks) {
                const int slot = ks * 4 + (lane >> 4);
                bf16x8 af[2], bfv[2];
                #pragma unroll
                for (int m = 0; m < 2; ++m) {
                    int row = wp * 32 + m * 16 + (lane & 15);
                    af[m] = *(const bf16x8*)((const char*)(&Asm[cur][row][0]) + ((slot ^ (row & 7)) << 4));
                }
                #pragma unroll
                for (int n = 0; n < 2; ++n) {
                    int row = wq * 32 + n * 16 + (lane & 15);
                    bfv[n] = *(const bf16x8*)((const char*)(&Bsm[cur][row][0]) + ((slot ^ (row & 7)) << 4));
                }
                // A,B frags use IDENTICAL lane->(row,k-slot) fill: any hw k-permutation
                // hits both operands -> dot invariant (numerics proven R7/R8).
                #pragma unroll
                for (int m = 0; m < 2; ++m)
                    #pragma unroll
                    for (int n = 0; n < 2; ++n)
                        acc[m][n] = __builtin_amdgcn_mfma_f32_16x16x32_bf16(af[m], bfv[n], acc[m][n], 0, 0, 0);
            }
            if (c < 7) writeChunk(cur ^ 1);       // vmcnt wait lands here, after MFMA
            __syncthreads();
        }

        // C/D layout (m89-verified): col = lane&15, row = (lane>>4)*4 + i
        #pragma unroll
        for (int m = 0; m < 2; ++m) {
            int p0 = pBase + wp * 32 + m * 16 + (lane >> 4) * 4;
            #pragma unroll
            for (int n = 0; n < 2; ++n) {
                int q = qBase + wq * 32 + n * 16 + (lane & 15);
                #pragma unroll
                for (int i = 0; i < 4; ++i)
                    GtH[(size_t)(p0 + i) * 512 + q] = acc[m][n][i];
            }
        }
    } else if (b < 192) {
        // logits[row] = attn_w[row,:].[embed|hidden] + attn_b[row]
        const float* embed = embed_table + (size_t)inputId[0] * H;
        int row = (b - 128) * 8 + w;
        const float* wrow = attn_w + (size_t)row * (2 * H);
        float acc = 0.f;
        #pragma unroll
        for (int it = 0; it < 8; ++it) {
            int base = it * 256 + lane * 4;
            float4 wv = *(const float4*)(wrow + base);
            float4 cv = (it < 4) ? *(const float4*)(embed + base)
                                 : *(const float4*)(hidden + (base - H));
            acc += wv.x * cv.x + wv.y * cv.y + wv.z * cv.z + wv.w * cv.w;
        }
        acc = wave_reduce_sum(acc);
        if (lane == 0) logits[row] = acc + attn_b[row];
    } else {
        // y1[row] = W1[row,:].embed + comb_b[row]; 16 rows/block
        const float* embed = embed_table + (size_t)inputId[0] * H;
        #pragma unroll
        for (int rr = 0; rr < 2; ++rr) {
            int row = (b - 192) * 16 + w * 2 + rr;
            const float* wrow = comb_w + (size_t)row * (2 * H);   // W1 half
            float acc = 0.f;
            #pragma unroll
            for (int it = 0; it < 4; ++it) {
                int base = it * 256 + lane * 4;
                float4 wv = *(const float4*)(wrow + base);
                float4 evv = *(const float4*)(embed + base);
                acc += wv.x * evv.x + wv.y * evv.y + wv.z * evv.z + wv.w * evv.w;
            }
            acc = wave_reduce_sum(acc);
            if (lane == 0) y1[row] = acc + comb_b[row];
        }
    }
}

// ================= Node 2: softmax + x = relu(y1 + (Gt0+Gt1).w) =================
// 128 blocks x 256; block b owns x rows [b*8, b*8+8) (2 rows/wave).
__global__ __launch_bounds__(256)
void node2(float* __restrict__ ws, float* __restrict__ d_out) {
    const float* logits = ws + WS_LOGITS;
    const float* y1     = ws + WS_Y1;
    const float* Gt0    = ws + WS_GT;
    const float* Gt1    = ws + WS_GT + GT_HALF;
    float* x = ws + WS_X;

    __shared__ float wsm[MAXLEN];
    __shared__ float red[4];
    const int tid = threadIdx.x, lane = tid & 63, wid = tid >> 6;
    const int b = blockIdx.x;

    float l0 = logits[tid], l1 = logits[tid + 256];
    float m = wave_reduce_max(fmaxf(l0, l1));
    if (lane == 0) red[wid] = m;
    __syncthreads();
    m = fmaxf(fmaxf(red[0], red[1]), fmaxf(red[2], red[3]));
    __syncthreads();
    float e0 = expf(l0 - m), e1 = expf(l1 - m);
    float s = wave_reduce_sum(e0 + e1);
    if (lane == 0) red[wid] = s;
    __syncthreads();
    s = red[0] + red[1] + red[2] + red[3];
    float inv = 1.f / s;
    float w0 = e0 * inv, w1 = e1 * inv;
    wsm[tid] = w0;
    wsm[tid + 256] = w1;
    if (b == 0) {                        // attnWeights (exact fp32)
        d_out[2048 + tid] = w0;
        d_out[2048 + 256 + tid] = w1;
    }
    __syncthreads();

    #pragma unroll
    for (int rr = 0; rr < 2; ++rr) {
        int row = b * 8 + wid * 2 + rr;                 // 0..1023
        const float* g0 = Gt0 + (size_t)row * 512;
        const float* g1 = Gt1 + (size_t)row * 512;
        float acc = 0.f;
        #pragma unroll
        for (int i = 0; i < 8; ++i) {
            int k = lane + 64 * i;
            acc += (g0[k] + g1[k]) * wsm[k];
        }
        acc = wave_reduce_sum(acc);
        if (lane == 0) x[row] = fmaxf(y1[row] + acc, 0.f);
    }
}

// ================= Node 3: GRU (h0 = 0 -> gh = b_hh) =================
__global__ __launch_bounds__(256)
void node3(const float* __restrict__ w_ih,
           const float* __restrict__ b_ih,
           const float* __restrict__ b_hh,
           const float* __restrict__ ws,
           float* __restrict__ d_out) {
    const float* x = ws + WS_X;
    int lane = threadIdx.x & 63;
    int j = blockIdx.x * 4 + (threadIdx.x >> 6);        // 0..1023
    float acc0 = 0.f, acc1 = 0.f, acc2 = 0.f;
    const float* wr = w_ih + (size_t)j * H;
    const float* wz = w_ih + (size_t)(H + j) * H;
    const float* wn = w_ih + (size_t)(2 * H + j) * H;
    #pragma unroll
    for (int it = 0; it < 4; ++it) {
        int base = it * 256 + lane * 4;
        float4 xv = *(const float4*)(x + base);
        float4 a = *(const float4*)(wr + base);
        float4 c = *(const float4*)(wz + base);
        float4 d = *(const float4*)(wn + base);
        acc0 += a.x * xv.x + a.y * xv.y + a.z * xv.z + a.w * xv.w;
        acc1 += c.x * xv.x + c.y * xv.y + c.z * xv.z + c.w * xv.w;
        acc2 += d.x * xv.x + d.y * xv.y + d.z * xv.z + d.w * xv.w;
    }
    #pragma unroll
    for (int off = 32; off; off >>= 1) {
        acc0 += __shfl_xor(acc0, off);
        acc1 += __shfl_xor(acc1, off);
        acc2 += __shfl_xor(acc2, off);
    }
    if (lane == 0) {
        float gi_r = acc0 + b_ih[j];
        float gi_z = acc1 + b_ih[H + j];
        float gi_n = acc2 + b_ih[2 * H + j];
        float r = 1.f / (1.f + expf(-(gi_r + b_hh[j])));
        float zz = 1.f / (1.f + expf(-(gi_z + b_hh[H + j])));
        float n = tanhf(gi_n + r * b_hh[2 * H + j]);
        float hnew = (1.f - zz) * n;                    // + z*h0, h0 = 0
        float outv = 1.f / (1.f + expf(-hnew));
        d_out[j] = outv;
        d_out[H + j] = hnew;
    }
}

// ================= Fallback (R2-proven 4-kernel path, used if ws too small) =================
__global__ void fb_kA(const int* __restrict__ inputId, const float* __restrict__ embed_table,
                      const float* __restrict__ hidden, const float* __restrict__ attn_w,
                      const float* __restrict__ attn_b, float* __restrict__ logits) {
    int lane = threadIdx.x & 63;
    int row = blockIdx.x * 4 + (threadIdx.x >> 6);
    const float* embed = embed_table + (size_t)inputId[0] * H;
    const float* wrow = attn_w + (size_t)row * (2 * H);
    float acc = 0.f;
    #pragma unroll
    for (int it = 0; it < 8; ++it) {
        int base = it * 256 + lane * 4;
        float4 wv = *(const float4*)(wrow + base);
        float4 cv = (it < 4) ? *(const float4*)(embed + base)
                             : *(const float4*)(hidden + (base - H));
        acc += wv.x * cv.x + wv.y * cv.y + wv.z * cv.z + wv.w * cv.w;
    }
    acc = wave_reduce_sum(acc);
    if (lane == 0) logits[row] = acc + attn_b[row];
}
__global__ void fb_kB(const float* __restrict__ logits, const float* __restrict__ enc,
                      float* __restrict__ attnApplied, float* __restrict__ out_w) {
    __shared__ float w_lds[MAXLEN];
    __shared__ float red[4];
    __shared__ float part[8][32];
    int tid = threadIdx.x, lane = tid & 63, wid = tid >> 6;
    float l0 = logits[tid], l1 = logits[tid + 256];
    float m = wave_reduce_max(fmaxf(l0, l1));
    if (lane == 0) red[wid] = m;
    __syncthreads();
    m = fmaxf(fmaxf(red[0], red[1]), fmaxf(red[2], red[3]));
    __syncthreads();
    float e0 = expf(l0 - m), e1 = expf(l1 - m);
    float s = wave_reduce_sum(e0 + e1);
    if (lane == 0) red[wid] = s;
    __syncthreads();
    s = red[0] + red[1] + red[2] + red[3];
    float inv = 1.f / s;
    float w0 = e0 * inv, w1 = e1 * inv;
    w_lds[tid] = w0; w_lds[tid + 256] = w1;
    if (blockIdx.x == 0) { out_w[tid] = w0; out_w[tid + 256] = w1; }
    __syncthreads();
    int c = tid & 31, ks = tid >> 5;
    int col = blockIdx.x * 32 + c;
    float acc = 0.f;
    for (int k = ks; k < MAXLEN; k += 8) acc += w_lds[k] * enc[(size_t)k * H + col];
    part[ks][c] = acc;
    __syncthreads();
    if (tid < 32) {
        float t = 0.f;
        #pragma unroll
        for (int i = 0; i < 8; ++i) t += part[i][tid];
        attnApplied[blockIdx.x * 32 + tid] = t;
    }
}
__global__ void fb_kC(const int* __restrict__ inputId, const float* __restrict__ embed_table,
                      const float* __restrict__ attnApplied, const float* __restrict__ comb_w,
                      const float* __restrict__ comb_b, float* __restrict__ x) {
    int lane = threadIdx.x & 63;
    int row = blockIdx.x * 4 + (threadIdx.x >> 6);
    const float* embed = embed_table + (size_t)inputId[0] * H;
    const float* wrow = comb_w + (size_t)row * (2 * H);
    float acc = 0.f;
    #pragma unroll
    for (int it = 0; it < 8; ++it) {
        int base = it * 256 + lane * 4;
        float4 wv = *(const float4*)(wrow + base);
        float4 cv = (it < 4) ? *(const float4*)(embed + base)
                             : *(const float4*)(attnApplied + (base - H));
        acc += wv.x * cv.x + wv.y * cv.y + wv.z * cv.z + wv.w * cv.w;
    }
    acc = wave_reduce_sum(acc);
    if (lane == 0) x[row] = fmaxf(acc + comb_b[row], 0.f);
}
__global__ void fb_kD(const float* __restrict__ w_ih, const float* __restrict__ b_ih,
                      const float* __restrict__ b_hh, const float* __restrict__ x,
                      float* __restrict__ d_out) {
    int lane = threadIdx.x & 63;
    int j = blockIdx.x * 4 + (threadIdx.x >> 6);
    float acc0 = 0.f, acc1 = 0.f, acc2 = 0.f;
    const float* wr = w_ih + (size_t)j * H;
    const float* wz = w_ih + (size_t)(H + j) * H;
    const float* wn = w_ih + (size_t)(2 * H + j) * H;
    #pragma unroll
    for (int it = 0; it < 4; ++it) {
        int base = it * 256 + lane * 4;
        float4 xv = *(const float4*)(x + base);
        float4 a = *(const float4*)(wr + base);
        float4 c = *(const float4*)(wz + base);
        float4 d = *(const float4*)(wn + base);
        acc0 += a.x * xv.x + a.y * xv.y + a.z * xv.z + a.w * xv.w;
        acc1 += c.x * xv.x + c.y * xv.y + c.z * xv.z + c.w * xv.w;
        acc2 += d.x * xv.x + d.y * xv.y + d.z * xv.z + d.w * xv.w;
    }
    #pragma unroll
    for (int off = 32; off; off >>= 1) {
        acc0 += __shfl_xor(acc0, off);
        acc1 += __shfl_xor(acc1, off);
        acc2 += __shfl_xor(acc2, off);
    }
    if (lane == 0) {
        float gi_r = acc0 + b_ih[j];
        float gi_z = acc1 + b_ih[H + j];
        float gi_n = acc2 + b_ih[2 * H + j];
        float r = 1.f / (1.f + expf(-(gi_r + b_hh[j])));
        float z = 1.f / (1.f + expf(-(gi_z + b_hh[H + j])));
        float n = tanhf(gi_n + r * b_hh[2 * H + j]);
        float hnew = (1.f - z) * n;
        float outv = 1.f / (1.f + expf(-hnew));
        d_out[j] = outv;
        d_out[H + j] = hnew;
    }
}

extern "C" void kernel_launch(void* const* d_in, const int* in_sizes, int n_in,
                              void* d_out, int out_size, void* d_ws, size_t ws_size,
                              hipStream_t stream) {
    const int*   inputId     = (const int*)d_in[0];
    const float* hidden      = (const float*)d_in[1];
    const float* enc         = (const float*)d_in[2];
    const float* embed_table = (const float*)d_in[3];
    const float* attn_w      = (const float*)d_in[4];
    const float* attn_b      = (const float*)d_in[5];
    const float* comb_w      = (const float*)d_in[6];
    const float* comb_b      = (const float*)d_in[7];
    const float* w_ih        = (const float*)d_in[8];
    // d_in[9] = w_hh dead: h0 == 0 -> gh = b_hh
    const float* b_ih        = (const float*)d_in[10];
    const float* b_hh        = (const float*)d_in[11];

    float* out = (float*)d_out;   // [0:1024) out, [1024:2048) h_new, [2048:2560) attnWeights
    float* ws  = (float*)d_ws;

    if (ws_size >= (size_t)WS_FLOATS * sizeof(float)) {
        node1<<<256, 512, 0, stream>>>(inputId, hidden, enc, embed_table,
                                       attn_w, attn_b, comb_w, comb_b, ws);
        node2<<<128, 256, 0, stream>>>(ws, out);
        node3<<<256, 256, 0, stream>>>(w_ih, b_ih, b_hh, ws, out);
    } else {
        float* logits      = ws;
        float* attnApplied = ws + 512;
        float* x           = ws + 2048;
        fb_kA<<<128, 256, 0, stream>>>(inputId, embed_table, hidden, attn_w, attn_b, logits);
        fb_kB<<<32,  256, 0, stream>>>(logits, enc, attnApplied, out + 2048);
        fb_kC<<<256, 256, 0, stream>>>(inputId, embed_table, attnApplied, comb_w, comb_b, x);
        fb_kD<<<256, 256, 0, stream>>>(w_ih, b_ih, b_hh, x, out);
    }
}